// Round 3
// baseline (346.863 us; speedup 1.0000x reference)
//
#include <hip/hip_runtime.h>
#include <stdint.h>

typedef _Float16 half8 __attribute__((ext_vector_type(8)));
typedef float float4v __attribute__((ext_vector_type(4)));

#define C_IN 64
#define C_OUT 128
#define H_IN 256
#define W_IN 256
#define H_OUT 254
#define W_OUT 254

// ---------------------------------------------------------------------------
// Pack conv_weight (OIHW fp32, [128][64][3][3]) into fp16 Bp[co][k] with
// k = (kh*3+kw)*64 + cin   (K reordered so one K-step of 64 = one (kh,kw) tap)
// ---------------------------------------------------------------------------
__global__ void pack_w_kernel(const float* __restrict__ w, _Float16* __restrict__ Bp) {
    int idx = blockIdx.x * 256 + threadIdx.x;          // 128*576 = 73728
    if (idx >= C_OUT * 576) return;
    int co  = idx / 576;
    int kp  = idx - co * 576;
    int s   = kp >> 6;          // tap index 0..8
    int cin = kp & 63;
    int kh  = s / 3, kw = s - kh * 3;
    Bp[idx] = (_Float16)w[(co * 64 + cin) * 9 + kh * 3 + kw];
}

// ---------------------------------------------------------------------------
// Transpose x: NCHW fp32 -> NHWC fp16  (x16[n][h][w][c], c innermost = 128 B)
// ---------------------------------------------------------------------------
__global__ __launch_bounds__(256)
void nchw_to_nhwc_kernel(const float* __restrict__ x, _Float16* __restrict__ x16) {
    __shared__ float t[64][65];
    const int tid = threadIdx.x;
    const int w0 = blockIdx.x * 64;
    const int h  = blockIdx.y;
    const int n  = blockIdx.z;

    const int c  = tid >> 2;            // 0..63
    const int wq = (tid & 3) * 16;      // 0,16,32,48
    const float* src = x + (((size_t)(n * 64 + c) * H_IN + h) * W_IN + w0 + wq);
#pragma unroll
    for (int j = 0; j < 4; ++j) {
        float4v v = *(const float4v*)(src + j * 4);
#pragma unroll
        for (int u = 0; u < 4; ++u) t[c][wq + j * 4 + u] = v[u];
    }
    __syncthreads();

    _Float16* dst = x16 + ((size_t)(n * 256 + h) * 256 + w0) * 64;
#pragma unroll
    for (int k = 0; k < 2; ++k) {
        int v = tid + k * 256;
        int w = v >> 3, c0 = (v & 7) * 8;
        half8 hv;
#pragma unroll
        for (int u = 0; u < 8; ++u) hv[u] = (_Float16)t[c0 + u][w];
        *(half8*)(dst + (size_t)w * 64 + c0) = hv;
    }
}

// XOR-swizzled LDS byte offset for [row][64 fp16] tiles (rows = 128 B).
__device__ __forceinline__ int swz(int row, int kbyte) {
    return row * 128 + (kbyte ^ ((row & 7) << 4));
}

// ---------------------------------------------------------------------------
// v3 fused conv + bias + min_c + tanh(tanh(.))
// Same geometry as v2 (A staged once via global_load_lds, 9 taps from LDS,
// B straight from L2) but with an EXPLICIT depth-1 register pipeline on the
// B fragments across the 18 (s,h) groups so the L2 latency (~250 cyc) hides
// under the previous group's MFMA cluster.
// Block: 128 px (2 rows x 64 cols) x 128 co, 4 waves each 64px x 64ch.
// grid: (4, 127, 16)
// ---------------------------------------------------------------------------
#define A_ROWS 264   // 4 * 66

__global__ __launch_bounds__(256, 4)
void conv_v3_kernel(const _Float16* __restrict__ x16,
                    const _Float16* __restrict__ Bp,
                    const float* __restrict__ bias,
                    float* __restrict__ out) {
    __shared__ __align__(16) _Float16 Alds[A_ROWS * 64];   // 33792 B, swizzled
    __shared__ float minbuf[2][128];

    const int tid  = threadIdx.x;
    const int lane = tid & 63;
    const int wave = tid >> 6;
    const int ow0  = blockIdx.x * 64;
    const int oh0  = blockIdx.y * 2;
    const int nb   = blockIdx.z;

    // ---- stage A tile: rows oh0..oh0+3, cols ow0..ow0+65, 64 cin, fp16
    {
        const char* xb = (const char*)(x16 + (size_t)nb * (256 * 256 * 64));
        for (int i = tid; i < 2112; i += 256) {            // 2112 x 16 B = 33792
            int row = i >> 3;
            int kb  = (i & 7) << 4;
            int r   = (unsigned)row / 66u;
            int c   = row - r * 66;
            int ih  = oh0 + r;
            int iw  = ow0 + c; if (iw > W_IN - 1) iw = W_IN - 1;
            const char* src = xb + (((size_t)ih * 256 + iw) << 7)
                                 + (kb ^ ((row & 7) << 4));
            char* ldst = (char*)Alds + ((size_t)(i & ~63) << 4);   // wave-uniform
            __builtin_amdgcn_global_load_lds(
                (const __attribute__((address_space(1))) uint32_t*)src,
                (__attribute__((address_space(3))) uint32_t*)ldst,
                16, 0, 0);
        }
    }
    __syncthreads();

    const int wr = wave >> 1;       // pixel half (row of output pair)
    const int wc = wave & 1;        // channel half
    const int q  = lane >> 4;
    const int lr = lane & 15;

    float4v acc[4][4];
#pragma unroll
    for (int m = 0; m < 4; ++m)
#pragma unroll
        for (int n = 0; n < 4; ++n)
#pragma unroll
            for (int i = 0; i < 4; ++i) acc[m][n][i] = 0.0f;

    // per-lane B base: channel row (wc*64+lr)*1152 bytes + lane k-offset q*16
    const char* bp0 = (const char*)Bp + (size_t)(wc * 64 + lr) * 1152 + q * 16;

    // ---- depth-1 software-pipelined main loop over 18 (s,h) groups
    half8 bcur[4], bnext[4];
#pragma unroll
    for (int n = 0; n < 4; ++n)
        bcur[n] = *(const half8*)(bp0 + (size_t)n * 18432);   // group 0: s=0,h=0

#pragma unroll
    for (int g = 0; g < 18; ++g) {
        const int s  = g >> 1;
        const int h  = g & 1;
        const int kh = s / 3, kw = s - kh * 3;
        const int kb = h * 64 + q * 16;

        // prefetch next group's B fragments (independent of this group's MFMAs)
        if (g < 17) {
            const int gn = g + 1;
            const int sn = gn >> 1, hn = gn & 1;
            const int off = sn * 128 + hn * 64;
#pragma unroll
            for (int n = 0; n < 4; ++n)
                bnext[n] = *(const half8*)(bp0 + (size_t)n * 18432 + off);
        }

        // A fragments from LDS
        half8 a[4];
        const int arowbase = (wr + kh) * 66 + kw;
#pragma unroll
        for (int m = 0; m < 4; ++m) {
            int row = arowbase + m * 16 + lr;
            a[m] = *(const half8*)((const char*)Alds + swz(row, kb));
        }

#pragma unroll
        for (int m = 0; m < 4; ++m)
#pragma unroll
            for (int n = 0; n < 4; ++n)
                acc[m][n] = __builtin_amdgcn_mfma_f32_16x16x32_f16(a[m], bcur[n], acc[m][n], 0, 0, 0);

#pragma unroll
        for (int n = 0; n < 4; ++n)
            bcur[n] = bnext[n];     // static swap (loop fully unrolled)
    }

    // ---- epilogue: + bias, min over channels, double tanh
#pragma unroll
    for (int m = 0; m < 4; ++m) {
        float4v v;
#pragma unroll
        for (int n = 0; n < 4; ++n) {
            float bv = bias[wc * 64 + n * 16 + lr];
#pragma unroll
            for (int i = 0; i < 4; ++i) {
                float t = acc[m][n][i] + bv;
                v[i] = (n == 0) ? t : fminf(v[i], t);
            }
        }
#pragma unroll
        for (int off = 1; off < 16; off <<= 1)
#pragma unroll
            for (int i = 0; i < 4; ++i)
                v[i] = fminf(v[i], __shfl_xor(v[i], off, 64));
        if (lr == 0) {
#pragma unroll
            for (int i = 0; i < 4; ++i)
                minbuf[wc][wr * 64 + m * 16 + q * 4 + i] = v[i];
        }
    }
    __syncthreads();

    if (tid < 128) {
        int pr = tid >> 6, pc = tid & 63;
        int ow = ow0 + pc;
        if (ow < W_OUT) {
            float mv = fminf(minbuf[0][tid], minbuf[1][tid]);
            float r  = tanhf(tanhf(mv));
            out[((size_t)nb * H_OUT + (oh0 + pr)) * W_OUT + ow] = r;
        }
    }
}

// ---------------------------------------------------------------------------
// Round-1 fallback kernel (used only if ws_size can't hold x16)
// ---------------------------------------------------------------------------
__global__ __launch_bounds__(256, 2)
void conv_min_tanh_kernel(const float* __restrict__ x,
                          const _Float16* __restrict__ Bp,
                          const float* __restrict__ bias,
                          float* __restrict__ out) {
    __shared__ _Float16 Alds[128 * 64];
    __shared__ _Float16 Blds[128 * 64];
    __shared__ float minbuf[2][128];

    const int tid  = threadIdx.x;
    const int ow0  = blockIdx.x * 64;
    const int oh0  = blockIdx.y * 2;
    const int nb   = blockIdx.z;

    const int wave = tid >> 6;
    const int lane = tid & 63;
    const int wr   = wave >> 1;
    const int wc   = wave & 1;
    const int q    = lane >> 4;
    const int lr   = lane & 15;

    float4v acc[4][4];
#pragma unroll
    for (int m = 0; m < 4; ++m)
#pragma unroll
        for (int n = 0; n < 4; ++n)
#pragma unroll
            for (int i = 0; i < 4; ++i) acc[m][n][i] = 0.0f;

    const int spx = tid & 127;
    const int sgh = tid >> 7;
    const int sr  = spx >> 6, sc = spx & 63;
    const int sco = tid >> 1;
    const int spart = tid & 1;

    const int arow0 = wr * 64 + lr;
    const int brow0 = wc * 64 + lr;

    for (int s = 0; s < 9; ++s) {
        const int kh = s / 3, kw = s - kh * 3;
        __syncthreads();
        {
            int ih = oh0 + sr + kh;
            int iw = ow0 + sc + kw;
            if (iw > W_IN - 1) iw = W_IN - 1;
            const float* xp = x + (size_t)nb * (C_IN * H_IN * W_IN)
                                + (size_t)(sgh * 32) * (H_IN * W_IN)
                                + ih * W_IN + iw;
#pragma unroll
            for (int j = 0; j < 4; ++j) {
                int cin0 = sgh * 32 + j * 8;
                float f[8];
#pragma unroll
                for (int u = 0; u < 8; ++u) f[u] = xp[(size_t)u * (H_IN * W_IN)];
                xp += (size_t)8 * (H_IN * W_IN);
                half8 hv;
#pragma unroll
                for (int u = 0; u < 8; ++u) hv[u] = (_Float16)f[u];
                *(half8*)((char*)Alds + swz(spx, cin0 * 2)) = hv;
            }
        }
        {
            const half8* bp = (const half8*)(Bp + (size_t)sco * 576 + s * 64 + spart * 32);
#pragma unroll
            for (int j = 0; j < 4; ++j) {
                half8 bv = bp[j];
                *(half8*)((char*)Blds + swz(sco, spart * 64 + j * 16)) = bv;
            }
        }
        __syncthreads();
#pragma unroll
        for (int h = 0; h < 2; ++h) {
            const int kb = h * 64 + q * 16;
            half8 a[4], b[4];
#pragma unroll
            for (int m = 0; m < 4; ++m)
                a[m] = *(const half8*)((const char*)Alds + swz(arow0 + m * 16, kb));
#pragma unroll
            for (int n = 0; n < 4; ++n)
                b[n] = *(const half8*)((const char*)Blds + swz(brow0 + n * 16, kb));
#pragma unroll
            for (int m = 0; m < 4; ++m)
#pragma unroll
                for (int n = 0; n < 4; ++n)
                    acc[m][n] = __builtin_amdgcn_mfma_f32_16x16x32_f16(a[m], b[n], acc[m][n], 0, 0, 0);
        }
    }

#pragma unroll
    for (int m = 0; m < 4; ++m) {
        float4v v;
#pragma unroll
        for (int n = 0; n < 4; ++n) {
            float bv = bias[wc * 64 + n * 16 + lr];
#pragma unroll
            for (int i = 0; i < 4; ++i) {
                float t = acc[m][n][i] + bv;
                v[i] = (n == 0) ? t : fminf(v[i], t);
            }
        }
#pragma unroll
        for (int off = 1; off < 16; off <<= 1)
#pragma unroll
            for (int i = 0; i < 4; ++i)
                v[i] = fminf(v[i], __shfl_xor(v[i], off, 64));
        if (lr == 0) {
#pragma unroll
            for (int i = 0; i < 4; ++i)
                minbuf[wc][wr * 64 + m * 16 + q * 4 + i] = v[i];
        }
    }
    __syncthreads();

    if (tid < 128) {
        int pr = tid >> 6, pc = tid & 63;
        int ow = ow0 + pc;
        if (ow < W_OUT) {
            float mv = fminf(minbuf[0][tid], minbuf[1][tid]);
            float r  = tanhf(tanhf(mv));
            out[((size_t)nb * H_OUT + (oh0 + pr)) * W_OUT + ow] = r;
        }
    }
}

extern "C" void kernel_launch(void* const* d_in, const int* in_sizes, int n_in,
                              void* d_out, int out_size, void* d_ws, size_t ws_size,
                              hipStream_t stream) {
    const float* x    = (const float*)d_in[0];
    const float* w    = (const float*)d_in[1];
    const float* bias = (const float*)d_in[2];
    float* out        = (float*)d_out;

    const size_t x16_bytes = (size_t)16 * 256 * 256 * 64 * 2;   // 134 MB
    const size_t bp_bytes  = (size_t)128 * 576 * 2;             // 147 KB

    if (ws_size >= x16_bytes + bp_bytes) {
        _Float16* x16 = (_Float16*)d_ws;
        _Float16* Bp  = (_Float16*)((char*)d_ws + x16_bytes);
        pack_w_kernel<<<dim3(288), dim3(256), 0, stream>>>(w, Bp);
        nchw_to_nhwc_kernel<<<dim3(4, 256, 16), dim3(256), 0, stream>>>(x, x16);
        conv_v3_kernel<<<dim3(4, 127, 16), dim3(256), 0, stream>>>(x16, Bp, bias, out);
    } else {
        _Float16* Bp = (_Float16*)d_ws;
        pack_w_kernel<<<dim3(288), dim3(256), 0, stream>>>(w, Bp);
        conv_min_tanh_kernel<<<dim3(4, 127, 16), dim3(256), 0, stream>>>(x, Bp, bias, out);
    }
}

// Round 4
// 243.665 us; speedup vs baseline: 1.4235x; 1.4235x over previous
//
#include <hip/hip_runtime.h>
#include <stdint.h>

typedef _Float16 half8 __attribute__((ext_vector_type(8)));
typedef float float4v __attribute__((ext_vector_type(4)));

#define C_IN 64
#define C_OUT 128
#define H_IN 256
#define W_IN 256
#define H_OUT 254
#define W_OUT 254

// ---------------------------------------------------------------------------
// Pack conv_weight (OIHW fp32) into coalesced-fragment layout:
//   Bp2[g][co][q][e]  with g = (kh*3+kw)*2 + h,  cin = h*32 + q*8 + e
// One wave's fragment load (16 co x 4 q x 8 e) = 1 KB contiguous.
// ---------------------------------------------------------------------------
__global__ void pack_w_kernel(const float* __restrict__ w, _Float16* __restrict__ Bp2) {
    int idx = blockIdx.x * 256 + threadIdx.x;          // 128*576 = 73728
    if (idx >= C_OUT * 576) return;
    int co  = idx / 576;
    int kp  = idx - co * 576;
    int tap = kp >> 6;          // 0..8
    int cin = kp & 63;
    int kh  = tap / 3, kw = tap - kh * 3;
    int h   = cin >> 5;
    int q   = (cin >> 3) & 3;
    int e   = cin & 7;
    int g   = tap * 2 + h;
    size_t oidx = ((((size_t)g * 128 + co) * 4) + q) * 8 + e;
    Bp2[oidx] = (_Float16)w[(co * 64 + cin) * 9 + kh * 3 + kw];
}

// ---------------------------------------------------------------------------
// Transpose x: NCHW fp32 -> NHWC fp16  (x16[n][h][w][c], c innermost = 128 B)
// ---------------------------------------------------------------------------
__global__ __launch_bounds__(256)
void nchw_to_nhwc_kernel(const float* __restrict__ x, _Float16* __restrict__ x16) {
    __shared__ float t[64][65];
    const int tid = threadIdx.x;
    const int w0 = blockIdx.x * 64;
    const int h  = blockIdx.y;
    const int n  = blockIdx.z;

    const int c  = tid >> 2;            // 0..63
    const int wq = (tid & 3) * 16;      // 0,16,32,48
    const float* src = x + (((size_t)(n * 64 + c) * H_IN + h) * W_IN + w0 + wq);
#pragma unroll
    for (int j = 0; j < 4; ++j) {
        float4v v = *(const float4v*)(src + j * 4);
#pragma unroll
        for (int u = 0; u < 4; ++u) t[c][wq + j * 4 + u] = v[u];
    }
    __syncthreads();

    _Float16* dst = x16 + ((size_t)(n * 256 + h) * 256 + w0) * 64;
#pragma unroll
    for (int k = 0; k < 2; ++k) {
        int v = tid + k * 256;
        int w = v >> 3, c0 = (v & 7) * 8;
        half8 hv;
#pragma unroll
        for (int u = 0; u < 8; ++u) hv[u] = (_Float16)t[c0 + u][w];
        *(half8*)(dst + (size_t)w * 64 + c0) = hv;
    }
}

// XOR-swizzled LDS byte offset for [row][64 fp16] tiles (rows = 128 B).
__device__ __forceinline__ int swz(int row, int kbyte) {
    return row * 128 + (kbyte ^ ((row & 7) << 4));
}

// ---------------------------------------------------------------------------
// v4 fused conv + bias + min_c + tanh(tanh(.))
// A staged once via global_load_lds (33 KB, swizzled), 9 taps read shifted
// LDS rows. B from coalesced Bp2 (1 KB contiguous per wave-load, L2-hot)
// with a named depth-1 register pipeline across the 18 (tap,h) groups.
// __launch_bounds__(256,3): 170 reg/wave budget so the pipeline can live
// in registers (v3's (256,4) capped at 128 total; 64 AGPR acc left no room
// and the compiler was forced to sink the prefetch -> 302us latency-bound).
// Block: 128 px (2 rows x 64 cols) x 128 co, 4 waves each 64px x 64ch.
// grid: (4, 127, 16)
// ---------------------------------------------------------------------------
#define A_ROWS 264   // 4 * 66

__global__ __launch_bounds__(256, 3)
void conv_v4_kernel(const _Float16* __restrict__ x16,
                    const _Float16* __restrict__ Bp2,
                    const float* __restrict__ bias,
                    float* __restrict__ out) {
    __shared__ __align__(16) _Float16 Alds[A_ROWS * 64];   // 33792 B, swizzled
    __shared__ float minbuf[2][128];

    const int tid  = threadIdx.x;
    const int lane = tid & 63;
    const int wave = tid >> 6;
    const int ow0  = blockIdx.x * 64;
    const int oh0  = blockIdx.y * 2;
    const int nb   = blockIdx.z;

    // ---- stage A tile: rows oh0..oh0+3, cols ow0..ow0+65, 64 cin, fp16
    {
        const char* xb = (const char*)(x16 + (size_t)nb * (256 * 256 * 64));
        for (int i = tid; i < 2112; i += 256) {            // 2112 x 16 B = 33792
            int row = i >> 3;
            int kb  = (i & 7) << 4;
            int r   = (unsigned)row / 66u;
            int c   = row - r * 66;
            int ih  = oh0 + r;
            int iw  = ow0 + c; if (iw > W_IN - 1) iw = W_IN - 1;
            const char* src = xb + (((size_t)ih * 256 + iw) << 7)
                                 + (kb ^ ((row & 7) << 4));
            char* ldst = (char*)Alds + ((size_t)(i & ~63) << 4);   // wave-uniform
            __builtin_amdgcn_global_load_lds(
                (const __attribute__((address_space(1))) uint32_t*)src,
                (__attribute__((address_space(3))) uint32_t*)ldst,
                16, 0, 0);
        }
    }
    __syncthreads();

    const int wr = wave >> 1;       // pixel half (row of output pair)
    const int wc = wave & 1;        // channel half
    const int q  = lane >> 4;
    const int lr = lane & 15;

    float4v acc[4][4];
#pragma unroll
    for (int m = 0; m < 4; ++m)
#pragma unroll
        for (int n = 0; n < 4; ++n)
#pragma unroll
            for (int i = 0; i < 4; ++i) acc[m][n][i] = 0.0f;

    // per-lane B base inside a (g) slab: co = wc*64 + n*16 + lr, k-oct q.
    // slab stride 8 KB, frag stride 1 KB.
    const char* bp0 = (const char*)Bp2 + (size_t)(wc * 64 + lr) * 64 + q * 16;

    // ---- depth-1 software-pipelined main loop over 18 (tap,h) groups
    half8 bcur[4], bnext[4];
#pragma unroll
    for (int n = 0; n < 4; ++n)
        bcur[n] = *(const half8*)(bp0 + n * 1024);            // g = 0

#pragma unroll
    for (int g = 0; g < 18; ++g) {
        const int s  = g >> 1;
        const int h  = g & 1;
        const int kh = s / 3, kw = s - kh * 3;
        const int kb = h * 64 + q * 16;

        // prefetch next group's B fragments (coalesced 1KB per wave-load)
        if (g < 17) {
#pragma unroll
            for (int n = 0; n < 4; ++n)
                bnext[n] = *(const half8*)(bp0 + (size_t)(g + 1) * 8192 + n * 1024);
        }

        // A fragments from LDS
        half8 a[4];
        const int arowbase = (wr + kh) * 66 + kw;
#pragma unroll
        for (int m = 0; m < 4; ++m) {
            int row = arowbase + m * 16 + lr;
            a[m] = *(const half8*)((const char*)Alds + swz(row, kb));
        }

#pragma unroll
        for (int m = 0; m < 4; ++m)
#pragma unroll
            for (int n = 0; n < 4; ++n)
                acc[m][n] = __builtin_amdgcn_mfma_f32_16x16x32_f16(a[m], bcur[n], acc[m][n], 0, 0, 0);

#pragma unroll
        for (int n = 0; n < 4; ++n)
            bcur[n] = bnext[n];     // static swap (loop fully unrolled)
    }

    // ---- epilogue: + bias, min over channels, double tanh
#pragma unroll
    for (int m = 0; m < 4; ++m) {
        float4v v;
#pragma unroll
        for (int n = 0; n < 4; ++n) {
            float bv = bias[wc * 64 + n * 16 + lr];
#pragma unroll
            for (int i = 0; i < 4; ++i) {
                float t = acc[m][n][i] + bv;
                v[i] = (n == 0) ? t : fminf(v[i], t);
            }
        }
#pragma unroll
        for (int off = 1; off < 16; off <<= 1)
#pragma unroll
            for (int i = 0; i < 4; ++i)
                v[i] = fminf(v[i], __shfl_xor(v[i], off, 64));
        if (lr == 0) {
#pragma unroll
            for (int i = 0; i < 4; ++i)
                minbuf[wc][wr * 64 + m * 16 + q * 4 + i] = v[i];
        }
    }
    __syncthreads();

    if (tid < 128) {
        int pr = tid >> 6, pc = tid & 63;
        int ow = ow0 + pc;
        if (ow < W_OUT) {
            float mv = fminf(minbuf[0][tid], minbuf[1][tid]);
            float r  = tanhf(tanhf(mv));
            out[((size_t)nb * H_OUT + (oh0 + pr)) * W_OUT + ow] = r;
        }
    }
}

// ---------------------------------------------------------------------------
// Fallback kernel (used only if ws_size can't hold x16): conv straight from
// NCHW fp32, per-tap staging. ~450us but correct. Uses OLD flat B layout,
// so it packs its own Bp via pack_w_flat_kernel.
// ---------------------------------------------------------------------------
__global__ void pack_w_flat_kernel(const float* __restrict__ w, _Float16* __restrict__ Bp) {
    int idx = blockIdx.x * 256 + threadIdx.x;
    if (idx >= C_OUT * 576) return;
    int co  = idx / 576;
    int kp  = idx - co * 576;
    int s   = kp >> 6;
    int cin = kp & 63;
    int kh  = s / 3, kw = s - kh * 3;
    Bp[idx] = (_Float16)w[(co * 64 + cin) * 9 + kh * 3 + kw];
}

__global__ __launch_bounds__(256, 2)
void conv_min_tanh_kernel(const float* __restrict__ x,
                          const _Float16* __restrict__ Bp,
                          const float* __restrict__ bias,
                          float* __restrict__ out) {
    __shared__ _Float16 Alds[128 * 64];
    __shared__ _Float16 Blds[128 * 64];
    __shared__ float minbuf[2][128];

    const int tid  = threadIdx.x;
    const int ow0  = blockIdx.x * 64;
    const int oh0  = blockIdx.y * 2;
    const int nb   = blockIdx.z;

    const int wave = tid >> 6;
    const int lane = tid & 63;
    const int wr   = wave >> 1;
    const int wc   = wave & 1;
    const int q    = lane >> 4;
    const int lr   = lane & 15;

    float4v acc[4][4];
#pragma unroll
    for (int m = 0; m < 4; ++m)
#pragma unroll
        for (int n = 0; n < 4; ++n)
#pragma unroll
            for (int i = 0; i < 4; ++i) acc[m][n][i] = 0.0f;

    const int spx = tid & 127;
    const int sgh = tid >> 7;
    const int sr  = spx >> 6, sc = spx & 63;
    const int sco = tid >> 1;
    const int spart = tid & 1;

    const int arow0 = wr * 64 + lr;
    const int brow0 = wc * 64 + lr;

    for (int s = 0; s < 9; ++s) {
        const int kh = s / 3, kw = s - kh * 3;
        __syncthreads();
        {
            int ih = oh0 + sr + kh;
            int iw = ow0 + sc + kw;
            if (iw > W_IN - 1) iw = W_IN - 1;
            const float* xp = x + (size_t)nb * (C_IN * H_IN * W_IN)
                                + (size_t)(sgh * 32) * (H_IN * W_IN)
                                + ih * W_IN + iw;
#pragma unroll
            for (int j = 0; j < 4; ++j) {
                int cin0 = sgh * 32 + j * 8;
                float f[8];
#pragma unroll
                for (int u = 0; u < 8; ++u) f[u] = xp[(size_t)u * (H_IN * W_IN)];
                xp += (size_t)8 * (H_IN * W_IN);
                half8 hv;
#pragma unroll
                for (int u = 0; u < 8; ++u) hv[u] = (_Float16)f[u];
                *(half8*)((char*)Alds + swz(spx, cin0 * 2)) = hv;
            }
        }
        {
            const half8* bp = (const half8*)(Bp + (size_t)sco * 576 + s * 64 + spart * 32);
#pragma unroll
            for (int j = 0; j < 4; ++j) {
                half8 bv = bp[j];
                *(half8*)((char*)Blds + swz(sco, spart * 64 + j * 16)) = bv;
            }
        }
        __syncthreads();
#pragma unroll
        for (int h = 0; h < 2; ++h) {
            const int kb = h * 64 + q * 16;
            half8 a[4], b[4];
#pragma unroll
            for (int m = 0; m < 4; ++m)
                a[m] = *(const half8*)((const char*)Alds + swz(arow0 + m * 16, kb));
#pragma unroll
            for (int n = 0; n < 4; ++n)
                b[n] = *(const half8*)((const char*)Blds + swz(brow0 + n * 16, kb));
#pragma unroll
            for (int m = 0; m < 4; ++m)
#pragma unroll
                for (int n = 0; n < 4; ++n)
                    acc[m][n] = __builtin_amdgcn_mfma_f32_16x16x32_f16(a[m], b[n], acc[m][n], 0, 0, 0);
        }
    }

#pragma unroll
    for (int m = 0; m < 4; ++m) {
        float4v v;
#pragma unroll
        for (int n = 0; n < 4; ++n) {
            float bv = bias[wc * 64 + n * 16 + lr];
#pragma unroll
            for (int i = 0; i < 4; ++i) {
                float t = acc[m][n][i] + bv;
                v[i] = (n == 0) ? t : fminf(v[i], t);
            }
        }
#pragma unroll
        for (int off = 1; off < 16; off <<= 1)
#pragma unroll
            for (int i = 0; i < 4; ++i)
                v[i] = fminf(v[i], __shfl_xor(v[i], off, 64));
        if (lr == 0) {
#pragma unroll
            for (int i = 0; i < 4; ++i)
                minbuf[wc][wr * 64 + m * 16 + q * 4 + i] = v[i];
        }
    }
    __syncthreads();

    if (tid < 128) {
        int pr = tid >> 6, pc = tid & 63;
        int ow = ow0 + pc;
        if (ow < W_OUT) {
            float mv = fminf(minbuf[0][tid], minbuf[1][tid]);
            float r  = tanhf(tanhf(mv));
            out[((size_t)nb * H_OUT + (oh0 + pr)) * W_OUT + ow] = r;
        }
    }
}

extern "C" void kernel_launch(void* const* d_in, const int* in_sizes, int n_in,
                              void* d_out, int out_size, void* d_ws, size_t ws_size,
                              hipStream_t stream) {
    const float* x    = (const float*)d_in[0];
    const float* w    = (const float*)d_in[1];
    const float* bias = (const float*)d_in[2];
    float* out        = (float*)d_out;

    const size_t x16_bytes = (size_t)16 * 256 * 256 * 64 * 2;   // 134 MB
    const size_t bp_bytes  = (size_t)128 * 576 * 2;             // 147 KB

    if (ws_size >= x16_bytes + bp_bytes) {
        _Float16* x16 = (_Float16*)d_ws;
        _Float16* Bp2 = (_Float16*)((char*)d_ws + x16_bytes);
        pack_w_kernel<<<dim3(288), dim3(256), 0, stream>>>(w, Bp2);
        nchw_to_nhwc_kernel<<<dim3(4, 256, 16), dim3(256), 0, stream>>>(x, x16);
        conv_v4_kernel<<<dim3(4, 127, 16), dim3(256), 0, stream>>>(x16, Bp2, bias, out);
    } else {
        _Float16* Bp = (_Float16*)d_ws;
        pack_w_flat_kernel<<<dim3(288), dim3(256), 0, stream>>>(w, Bp);
        conv_min_tanh_kernel<<<dim3(4, 127, 16), dim3(256), 0, stream>>>(x, Bp, bias, out);
    }
}

// Round 5
// 176.108 us; speedup vs baseline: 1.9696x; 1.3836x over previous
//
#include <hip/hip_runtime.h>
#include <stdint.h>

typedef _Float16 half8 __attribute__((ext_vector_type(8)));
typedef float float4v __attribute__((ext_vector_type(4)));

#define C_IN 64
#define C_OUT 128
#define H_IN 256
#define W_IN 256
#define H_OUT 254
#define W_OUT 254

// ---------------------------------------------------------------------------
// Pack conv_weight (OIHW fp32) into coalesced-fragment layout:
//   Bp2[g][co][q][e]  with g = (kh*3+kw)*2 + h,  cin = h*32 + q*8 + e
// One wave's fragment load (16 co x 4 q x 8 e) = 1 KB contiguous.
// ---------------------------------------------------------------------------
__global__ void pack_w_kernel(const float* __restrict__ w, _Float16* __restrict__ Bp2) {
    int idx = blockIdx.x * 256 + threadIdx.x;          // 128*576 = 73728
    if (idx >= C_OUT * 576) return;
    int co  = idx / 576;
    int kp  = idx - co * 576;
    int tap = kp >> 6;          // 0..8
    int cin = kp & 63;
    int kh  = tap / 3, kw = tap - kh * 3;
    int h   = cin >> 5;
    int q   = (cin >> 3) & 3;
    int e   = cin & 7;
    int g   = tap * 2 + h;
    size_t oidx = ((((size_t)g * 128 + co) * 4) + q) * 8 + e;
    Bp2[oidx] = (_Float16)w[(co * 64 + cin) * 9 + kh * 3 + kw];
}

// ---------------------------------------------------------------------------
// v5 fused: NCHW fp32 read + transpose-stage + conv + bias + min_c + tanh^2.
// Block: 256 px (4 output rows x 64 cols) x 128 co. 4 waves, each 128px x 64co
// (8 m-frags x 4 n-frags, acc = 128 VGPR). A-tile staged once per block:
// 6 input rows x 68 cols x 64 cin fp16 = 52 KB LDS, XOR-swizzled, written via
// register-transpose of 8cin x 4px fp32 batches. B direct from L2-hot Bp2
// (1 KB coalesced per wave-frag-load); B-bytes/MFMA halved vs v4 so L2 BW
// (571 cyc/CU-step) now sits well under the MFMA line (1242 cyc/CU-step).
// grid: (4, 64, 16)
// ---------------------------------------------------------------------------
#define T_ROWS 6
#define T_COLS 68
#define A_ROWS (T_ROWS * T_COLS)   // 408 LDS rows of 64 fp16 (128 B)

__global__ __launch_bounds__(256, 2)
void conv_v5_kernel(const float* __restrict__ x,
                    const _Float16* __restrict__ Bp2,
                    const float* __restrict__ bias,
                    float* __restrict__ out) {
    __shared__ __align__(16) _Float16 Alds[A_ROWS * 64];   // 52224 B
    __shared__ float minbuf[2][256];

    const int tid  = threadIdx.x;
    const int lane = tid & 63;
    const int wave = tid >> 6;
    const int ow0  = blockIdx.x * 64;
    const int oh0  = blockIdx.y * 4;
    const int nb   = blockIdx.z;

    // ---- fused transpose-stage: x[n][cin][ih][iw] fp32 -> Alds[px][cin] fp16
    // item id = (cinoct 0..7) * 102 + (pxq 0..101); each: 8 float4 loads
    // (8 cin x 4 px), register transpose, 4 ds_write_b128 (swizzled).
    {
        const float* xb = x + (size_t)nb * (C_IN * H_IN * W_IN);
        for (int id = tid; id < 816; id += 256) {
            int cinoct = (unsigned)id / 102u;
            int pxq    = id - cinoct * 102;
            int row0   = pxq * 4;                    // LDS row of first px
            int r      = (unsigned)row0 / (unsigned)T_COLS;
            int c      = row0 - r * T_COLS;
            int ih     = oh0 + r; if (ih > H_IN - 1) ih = H_IN - 1;
            int iw     = ow0 + c; if (iw > W_IN - 4) iw = W_IN - 4;  // pad cols only
            const float* src = xb + ((size_t)(cinoct * 8) * (H_IN * W_IN))
                                  + (size_t)ih * W_IN + iw;
            float4v f[8];
#pragma unroll
            for (int j2 = 0; j2 < 8; ++j2)
                f[j2] = *(const float4v*)(src + (size_t)j2 * (H_IN * W_IN));
#pragma unroll
            for (int j = 0; j < 4; ++j) {
                int row = row0 + j;
                half8 hv;
#pragma unroll
                for (int u = 0; u < 8; ++u) hv[u] = (_Float16)f[u][j];
                *(half8*)((char*)Alds + row * 128
                          + ((cinoct * 16) ^ ((row & 7) << 4))) = hv;
            }
        }
    }
    __syncthreads();

    const int wr = wave >> 1;       // pixel half: px 0..127 / 128..255
    const int wc = wave & 1;        // channel half
    const int q  = lane >> 4;
    const int lr = lane & 15;

    float4v acc[8][4];
#pragma unroll
    for (int m = 0; m < 8; ++m)
#pragma unroll
        for (int n = 0; n < 4; ++n)
#pragma unroll
            for (int i = 0; i < 4; ++i) acc[m][n][i] = 0.0f;

    // per-lane B base: co = wc*64 + n*16 + lr, k-oct q. slab 8KB, frag 1KB.
    const char* bp0 = (const char*)Bp2 + (size_t)(wc * 64 + lr) * 64 + q * 16;

    half8 bcur[4], bnext[4];
#pragma unroll
    for (int n = 0; n < 4; ++n)
        bcur[n] = *(const half8*)(bp0 + n * 1024);            // g = 0

#pragma unroll
    for (int g = 0; g < 18; ++g) {
        const int s  = g >> 1;
        const int h  = g & 1;
        const int kh = s / 3, kw = s - kh * 3;
        const int kb = h * 64 + q * 16;

        if (g < 17) {
#pragma unroll
            for (int n = 0; n < 4; ++n)
                bnext[n] = *(const half8*)(bp0 + (size_t)(g + 1) * 8192 + n * 1024);
        }

        // A fragments: px = wr*128 + m*16 + lr -> input row/col + (kh,kw)
        half8 a[8];
#pragma unroll
        for (int m = 0; m < 8; ++m) {
            int px  = wr * 128 + m * 16 + lr;                 // 0..255
            int row = ((px >> 6) + kh) * T_COLS + (px & 63) + kw;
            a[m] = *(const half8*)((const char*)Alds + row * 128
                                   + (kb ^ ((row & 7) << 4)));
        }

#pragma unroll
        for (int m = 0; m < 8; ++m)
#pragma unroll
            for (int n = 0; n < 4; ++n)
                acc[m][n] = __builtin_amdgcn_mfma_f32_16x16x32_f16(a[m], bcur[n], acc[m][n], 0, 0, 0);

#pragma unroll
        for (int n = 0; n < 4; ++n)
            bcur[n] = bnext[n];
    }

    // ---- epilogue: + bias, min over channels (n-frags then 16 lanes), store
#pragma unroll
    for (int m = 0; m < 8; ++m) {
        float4v v;
#pragma unroll
        for (int n = 0; n < 4; ++n) {
            float bv = bias[wc * 64 + n * 16 + lr];
#pragma unroll
            for (int i = 0; i < 4; ++i) {
                float t = acc[m][n][i] + bv;
                v[i] = (n == 0) ? t : fminf(v[i], t);
            }
        }
#pragma unroll
        for (int off = 1; off < 16; off <<= 1)
#pragma unroll
            for (int i = 0; i < 4; ++i)
                v[i] = fminf(v[i], __shfl_xor(v[i], off, 64));
        if (lr == 0) {
#pragma unroll
            for (int i = 0; i < 4; ++i)
                minbuf[wc][wr * 128 + m * 16 + q * 4 + i] = v[i];
        }
    }
    __syncthreads();

    {
        int r = tid >> 6, c = tid & 63;
        int oh = oh0 + r, ow = ow0 + c;
        if (oh < H_OUT && ow < W_OUT) {
            float mv = fminf(minbuf[0][tid], minbuf[1][tid]);
            float rr = tanhf(tanhf(mv));
            out[((size_t)nb * H_OUT + oh) * W_OUT + ow] = rr;
        }
    }
}

extern "C" void kernel_launch(void* const* d_in, const int* in_sizes, int n_in,
                              void* d_out, int out_size, void* d_ws, size_t ws_size,
                              hipStream_t stream) {
    const float* x    = (const float*)d_in[0];
    const float* w    = (const float*)d_in[1];
    const float* bias = (const float*)d_in[2];
    float* out        = (float*)d_out;
    _Float16* Bp2     = (_Float16*)d_ws;   // 147456 B

    pack_w_kernel<<<dim3(288), dim3(256), 0, stream>>>(w, Bp2);
    conv_v5_kernel<<<dim3(4, 64, 16), dim3(256), 0, stream>>>(x, Bp2, bias, out);
}